// Round 8
// baseline (171.863 us; speedup 1.0000x reference)
//
#include <hip/hip_runtime.h>

#define LSEQ 384
#define NROWS 1536      // B*L
#define FDIM 640
#define HDIM 128
#define PART 196608     // 1536*128

// ws layout (float indices)
#define WS_FIP 0                 // 4 x PART (fi split-K partials)
#define WS_FJP (4*PART)          // 4 x PART (fj split-K partials)
#define WS_QC  (8*PART)
#define WS_FLAG (WS_QC + NROWS)  // int[1536]

// out layout (float indices)
#define OUT_PC    0
#define OUT_TC    4608
#define OUT_NET   9216
#define OUT_POT   10752
#define OUT_MASK  12288
#define OUT_EN    602112

// =========== Kernel 1: projections ===========
// grid 864: blocks 0..95   -> type A: H1 (BM=16, BN=128, full K, dbuf) + inline row epilogue
//           blocks 96..863 -> type B: fi/fj tiles (BM=32, BN=64, split-K=4, dbuf)
__global__ __launch_bounds__(256) void k1(const float* __restrict__ X,
                                          const float* __restrict__ W1,
                                          const float* __restrict__ sW1,
                                          const float* __restrict__ b1,
                                          const float* __restrict__ gam,
                                          const float* __restrict__ bet,
                                          const float* __restrict__ rmean,
                                          const float* __restrict__ rvar,
                                          const float* __restrict__ W2,
                                          const float* __restrict__ b2,
                                          const float* __restrict__ W3,
                                          const float* __restrict__ b3,
                                          const int* __restrict__ seq,
                                          float* __restrict__ out,
                                          float* __restrict__ ws) {
    __shared__ float smemf[9344];   // 37376 B union
    const int t = threadIdx.x;
    const int blk = blockIdx.x;

    if (blk == 0 && t < 4) out[OUT_EN + t] = 0.0f;   // energy zero (k2 atomicAdds)

    if (blk < 96) {
        // ---------------- type A ----------------
        float* As = smemf;            // dbuf 2 x [32][18] = 1152 f
        float* Bs = smemf + 1152;     // dbuf 2 x [32][128] = 8192 f
        const int m0 = blk * 16;
        const int a_r = t >> 4;           // 0..15
        const int a_c = (t & 15) * 2;     // 0..30
        const int b_r = t >> 5;           // 0..7
        const int b_c = (t & 31) * 4;     // 0..124
        const int tx = (t & 31) * 4;
        const int ty = (t >> 5) * 2;
        float acc[2][4] = {};

        float2 av = *(const float2*)&X[(m0 + a_r) * FDIM + a_c];
        float4 bv0 = *(const float4*)&W1[(b_r) * HDIM + b_c];
        float4 bv1 = *(const float4*)&W1[(b_r + 8) * HDIM + b_c];
        float4 bv2 = *(const float4*)&W1[(b_r + 16) * HDIM + b_c];
        float4 bv3 = *(const float4*)&W1[(b_r + 24) * HDIM + b_c];
        As[(a_c + 0) * 18 + a_r] = av.x;
        As[(a_c + 1) * 18 + a_r] = av.y;
        *(float4*)&Bs[(b_r) * 128 + b_c]      = bv0;
        *(float4*)&Bs[(b_r + 8) * 128 + b_c]  = bv1;
        *(float4*)&Bs[(b_r + 16) * 128 + b_c] = bv2;
        *(float4*)&Bs[(b_r + 24) * 128 + b_c] = bv3;
        __syncthreads();

        for (int it = 0; it < 20; it++) {
            const int buf = it & 1;
            if (it < 19) {
                const int kk = (it + 1) * 32;
                av  = *(const float2*)&X[(m0 + a_r) * FDIM + kk + a_c];
                bv0 = *(const float4*)&W1[(kk + b_r) * HDIM + b_c];
                bv1 = *(const float4*)&W1[(kk + b_r + 8) * HDIM + b_c];
                bv2 = *(const float4*)&W1[(kk + b_r + 16) * HDIM + b_c];
                bv3 = *(const float4*)&W1[(kk + b_r + 24) * HDIM + b_c];
            }
            const float* Ab = As + buf * 576;
            const float* Bb = Bs + buf * 4096;
#pragma unroll
            for (int k = 0; k < 32; k++) {
                float2 a = *(const float2*)&Ab[k * 18 + ty];
                float4 b = *(const float4*)&Bb[k * 128 + tx];
                acc[0][0] = fmaf(a.x, b.x, acc[0][0]);
                acc[0][1] = fmaf(a.x, b.y, acc[0][1]);
                acc[0][2] = fmaf(a.x, b.z, acc[0][2]);
                acc[0][3] = fmaf(a.x, b.w, acc[0][3]);
                acc[1][0] = fmaf(a.y, b.x, acc[1][0]);
                acc[1][1] = fmaf(a.y, b.y, acc[1][1]);
                acc[1][2] = fmaf(a.y, b.z, acc[1][2]);
                acc[1][3] = fmaf(a.y, b.w, acc[1][3]);
            }
            if (it < 19) {
                float* Aw = As + (buf ^ 1) * 576;
                float* Bw = Bs + (buf ^ 1) * 4096;
                Aw[(a_c + 0) * 18 + a_r] = av.x;
                Aw[(a_c + 1) * 18 + a_r] = av.y;
                *(float4*)&Bw[(b_r) * 128 + b_c]      = bv0;
                *(float4*)&Bw[(b_r + 8) * 128 + b_c]  = bv1;
                *(float4*)&Bw[(b_r + 16) * 128 + b_c] = bv2;
                *(float4*)&Bw[(b_r + 24) * 128 + b_c] = bv3;
                __syncthreads();
            }
        }
        __syncthreads();   // before aliasing smem as hs

        // BN epilogue -> hs [16][132]
        float* hs = smemf;
        {
            float4 b1v = *(const float4*)&b1[tx];
            float4 g4  = *(const float4*)&gam[tx];
            float4 be4 = *(const float4*)&bet[tx];
            float4 rm4 = *(const float4*)&rmean[tx];
            float4 rv4 = *(const float4*)&rvar[tx];
            float rs0 = 1.0f / sqrtf(rv4.x + 1e-5f);
            float rs1 = 1.0f / sqrtf(rv4.y + 1e-5f);
            float rs2 = 1.0f / sqrtf(rv4.z + 1e-5f);
            float rs3 = 1.0f / sqrtf(rv4.w + 1e-5f);
#pragma unroll
            for (int r = 0; r < 2; r++) {
                float v0 = g4.x * (fmaxf(acc[r][0] + b1v.x, 0.0f) - rm4.x) * rs0 + be4.x;
                float v1 = g4.y * (fmaxf(acc[r][1] + b1v.y, 0.0f) - rm4.y) * rs1 + be4.y;
                float v2 = g4.z * (fmaxf(acc[r][2] + b1v.z, 0.0f) - rm4.z) * rs2 + be4.z;
                float v3 = g4.w * (fmaxf(acc[r][3] + b1v.w, 0.0f) - rm4.w) * rs3 + be4.w;
                *(float4*)&hs[(ty + r) * 132 + tx] = make_float4(v0, v1, v2, v3);
            }
        }
        __syncthreads();

        // wave epilogue: 4 rows per wave
        const int w = t >> 6, lane = t & 63;
        float h0r[4], h1r[4], acc2[4];
#pragma unroll
        for (int r = 0; r < 4; r++) {
            h0r[r] = hs[(w * 4 + r) * 132 + lane];
            h1r[r] = hs[(w * 4 + r) * 132 + 64 + lane];
            acc2[r] = b2[lane];
        }
#pragma unroll
        for (int cc = 0; cc < 64; cc++) {
            float wv0 = W2[cc * 64 + lane];
            float wv1 = W2[(cc + 64) * 64 + lane];
#pragma unroll
            for (int r = 0; r < 4; r++) {
                float hv0 = __uint_as_float(__builtin_amdgcn_readlane(__float_as_uint(h0r[r]), cc));
                float hv1 = __uint_as_float(__builtin_amdgcn_readlane(__float_as_uint(h1r[r]), cc));
                acc2[r] = fmaf(hv0, wv0, acc2[r]);
                acc2[r] = fmaf(hv1, wv1, acc2[r]);
            }
        }
        float w30 = W3[lane * 3 + 0], w31 = W3[lane * 3 + 1], w32 = W3[lane * 3 + 2];
#pragma unroll
        for (int r = 0; r < 4; r++) {
            float h2 = fmaxf(acc2[r], 0.0f);
            float x0 = h2 * w30, x1 = h2 * w31, x2 = h2 * w32;
#pragma unroll
            for (int o = 32; o > 0; o >>= 1) {
                x0 += __shfl_xor(x0, o, 64);
                x1 += __shfl_xor(x1, o, 64);
                x2 += __shfl_xor(x2, o, 64);
            }
            if (lane == 0) {
                int row = m0 + w * 4 + r;
                float l0 = x0 + b3[0], l1 = x1 + b3[1], l2 = x2 + b3[2];
                float m = fmaxf(l0, fmaxf(l1, l2));
                float e0 = expf(l0 - m), e1 = expf(l1 - m), e2 = expf(l2 - m);
                float s = e0 + e1 + e2;
                float pc0 = e0 / s, pc1 = e1 / s, pc2 = e2 / s;
                out[OUT_PC + row * 3 + 0] = pc0;
                out[OUT_PC + row * 3 + 1] = pc1;
                out[OUT_PC + row * 3 + 2] = pc2;
                float net = pc0 - pc1;
                out[OUT_NET + row] = net;
                ws[WS_QC + row] = net;
                ((int*)(ws + WS_FLAG))[row] = (pc0 > pc2 ? 1 : 0) | (pc1 > pc2 ? 2 : 0);
                int sid = seq[row];
                float c0 = (sid == 6 || sid == 8 || sid == 14) ? 1.0f : 0.0f;
                float c1 = (sid == 2 || sid == 3) ? 1.0f : 0.0f;
                out[OUT_TC + row * 3 + 0] = c0;
                out[OUT_TC + row * 3 + 1] = c1;
                out[OUT_TC + row * 3 + 2] = (c0 == 0.0f && c1 == 0.0f) ? 1.0f : 0.0f;
            }
        }
    } else {
        // ---------------- type B: fi/fj split-K=4 ----------------
        float* As = smemf;            // dbuf 2 x [32][34] = 2176 f
        float* Bs = smemf + 2176;     // dbuf 2 x [32][64] = 4096 f
        const int bi = blk - 96;
        const int mt = bi >> 4, rem = bi & 15;
        const int mat = rem >> 3, half = (rem >> 2) & 1, kz = rem & 3;
        const int m0 = mt * 32, n0 = half * 64;
        const float* W = sW1 + mat * 640 * 128;
        float* O = ws + (mat == 0 ? WS_FIP : WS_FJP) + kz * PART;

        const int a_r = t >> 3, a_c = (t & 7) * 4;
        const int b_r = t >> 4, b_c = (t & 15) * 4;
        const int tx = (t & 15) * 4, ty = (t >> 4) * 2;
        const int k0 = kz * 160;

        float acc[2][4] = {};

        float4 av  = *(const float4*)&X[(m0 + a_r) * FDIM + k0 + a_c];
        float4 bv0 = *(const float4*)&W[(k0 + b_r) * HDIM + n0 + b_c];
        float4 bv1 = *(const float4*)&W[(k0 + b_r + 16) * HDIM + n0 + b_c];
        As[(a_c + 0) * 34 + a_r] = av.x;
        As[(a_c + 1) * 34 + a_r] = av.y;
        As[(a_c + 2) * 34 + a_r] = av.z;
        As[(a_c + 3) * 34 + a_r] = av.w;
        *(float4*)&Bs[b_r * 64 + b_c]        = bv0;
        *(float4*)&Bs[(b_r + 16) * 64 + b_c] = bv1;
        __syncthreads();

        for (int it = 0; it < 5; it++) {
            const int buf = it & 1;
            if (it < 4) {
                const int kk = k0 + (it + 1) * 32;
                av  = *(const float4*)&X[(m0 + a_r) * FDIM + kk + a_c];
                bv0 = *(const float4*)&W[(kk + b_r) * HDIM + n0 + b_c];
                bv1 = *(const float4*)&W[(kk + b_r + 16) * HDIM + n0 + b_c];
            }
            const float* Ab = As + buf * 1088;
            const float* Bb = Bs + buf * 2048;
#pragma unroll
            for (int k = 0; k < 32; k++) {
                float2 a = *(const float2*)&Ab[k * 34 + ty];
                float4 b = *(const float4*)&Bb[k * 64 + tx];
                acc[0][0] = fmaf(a.x, b.x, acc[0][0]);
                acc[0][1] = fmaf(a.x, b.y, acc[0][1]);
                acc[0][2] = fmaf(a.x, b.z, acc[0][2]);
                acc[0][3] = fmaf(a.x, b.w, acc[0][3]);
                acc[1][0] = fmaf(a.y, b.x, acc[1][0]);
                acc[1][1] = fmaf(a.y, b.y, acc[1][1]);
                acc[1][2] = fmaf(a.y, b.z, acc[1][2]);
                acc[1][3] = fmaf(a.y, b.w, acc[1][3]);
            }
            if (it < 4) {
                float* Aw = As + (buf ^ 1) * 1088;
                float* Bw = Bs + (buf ^ 1) * 2048;
                Aw[(a_c + 0) * 34 + a_r] = av.x;
                Aw[(a_c + 1) * 34 + a_r] = av.y;
                Aw[(a_c + 2) * 34 + a_r] = av.z;
                Aw[(a_c + 3) * 34 + a_r] = av.w;
                *(float4*)&Bw[b_r * 64 + b_c]        = bv0;
                *(float4*)&Bw[(b_r + 16) * 64 + b_c] = bv1;
                __syncthreads();
            }
        }
#pragma unroll
        for (int r = 0; r < 2; r++) {
            float4 v = make_float4(acc[r][0], acc[r][1], acc[r][2], acc[r][3]);
            *(float4*)&O[(m0 + ty + r) * HDIM + n0 + tx] = v;
        }
    }
}

// =========== Kernel 2: conv + pair sweep (4 rows/block) ===========
__device__ __forceinline__ float mlp_eval(const float* __restrict__ fiP, const float* __restrict__ fjP,
                                          int gi, int gj, float D,
                                          float dv0, float dv1, float sb0, float sb1v,
                                          float b2v, float w3l, const float* __restrict__ sW2, int lane) {
    const long bi0 = (long)gi * 128 + lane;
    const long bj0 = (long)gj * 128 + lane;
    float fi0 = fiP[bi0]      + fiP[PART + bi0]      + fiP[2 * PART + bi0]      + fiP[3 * PART + bi0];
    float fi1 = fiP[bi0 + 64] + fiP[PART + bi0 + 64] + fiP[2 * PART + bi0 + 64] + fiP[3 * PART + bi0 + 64];
    float fj0 = fjP[bj0]      + fjP[PART + bj0]      + fjP[2 * PART + bj0]      + fjP[3 * PART + bj0];
    float fj1 = fjP[bj0 + 64] + fjP[PART + bj0 + 64] + fjP[2 * PART + bj0 + 64] + fjP[3 * PART + bj0 + 64];
    float h0 = fmaxf(fi0 + fj0 + D * dv0 + sb0,  0.0f);
    float h1 = fmaxf(fi1 + fj1 + D * dv1 + sb1v, 0.0f);
    float a0 = 0.0f, a1 = 0.0f;
#pragma unroll 8
    for (int cc = 0; cc < 64; cc++) {
        float hv0 = __uint_as_float(__builtin_amdgcn_readlane(__float_as_uint(h0), cc));
        float hv1 = __uint_as_float(__builtin_amdgcn_readlane(__float_as_uint(h1), cc));
        a0 = fmaf(hv0, sW2[cc * 64 + lane], a0);
        a1 = fmaf(hv1, sW2[(cc + 64) * 64 + lane], a1);
    }
    float x = fmaxf(a0 + a1 + b2v, 0.0f) * w3l;
#pragma unroll
    for (int o = 32; o > 0; o >>= 1) x += __shfl_xor(x, o, 64);
    return x;
}

// grid 388: blocks 0..3 conv (one per batch); blocks 4..387 -> 4 mask rows each.
__global__ __launch_bounds__(256) void k2(const float* __restrict__ S,
                                          const float* __restrict__ ws,
                                          const float* __restrict__ sW1,
                                          const float* __restrict__ sb1,
                                          const float* __restrict__ sW2,
                                          const float* __restrict__ sb2,
                                          const float* __restrict__ sW3,
                                          const float* __restrict__ sb3,
                                          const float* __restrict__ c1w, const float* __restrict__ c1b,
                                          const float* __restrict__ c2w, const float* __restrict__ c2b,
                                          const float* __restrict__ c3w, const float* __restrict__ c3b,
                                          float* __restrict__ out) {
    __shared__ char smem[6592];
    const int t = threadIdx.x;
    const int bi = blockIdx.x;

    if (bi < 4) {
        float* p0h = (float*)smem;   // 392 floats: positions -4..387, zero-padded
        const int b = bi;
        for (int idx = t; idx < 392; idx += 256)
            p0h[idx] = (idx >= 4 && idx < 388) ? out[OUT_NET + b * LSEQ + (idx - 4)] : 0.0f;
        __syncthreads();
        for (int pos = t; pos < LSEQ; pos += 256) {
            float p2v[8][3];
#pragma unroll
            for (int o2 = 0; o2 < 8; o2++) {
                float cb = c2b[o2];
#pragma unroll
                for (int d1 = 0; d1 < 3; d1++) p2v[o2][d1] = cb;
            }
            for (int i = 0; i < 16; i++) {
                float p1v[5];
#pragma unroll
                for (int d2 = 0; d2 < 5; d2++) {
                    int q2 = pos - 2 + d2;
                    float a = c1b[i];
#pragma unroll
                    for (int k = 0; k < 5; k++)
                        a = fmaf(p0h[q2 + 2 + k], c1w[i * 5 + k], a);
                    p1v[d2] = (q2 >= 0 && q2 < LSEQ) ? fmaxf(a, 0.0f) : 0.0f;
                }
#pragma unroll
                for (int o2 = 0; o2 < 8; o2++) {
#pragma unroll
                    for (int d1 = 0; d1 < 3; d1++) {
#pragma unroll
                        for (int k = 0; k < 3; k++)
                            p2v[o2][d1] = fmaf(p1v[d1 + k], c2w[(o2 * 16 + i) * 3 + k], p2v[o2][d1]);
                    }
                }
            }
            float acc3 = c3b[0];
#pragma unroll
            for (int o2 = 0; o2 < 8; o2++) {
#pragma unroll
                for (int k = 0; k < 3; k++) {
                    int q1 = pos - 1 + k;
                    float pv = (q1 >= 0 && q1 < LSEQ) ? fmaxf(p2v[o2][k], 0.0f) : 0.0f;
                    acc3 = fmaf(pv, c3w[o2 * 3 + k], acc3);
                }
            }
            out[OUT_POT + b * LSEQ + pos] = acc3;
        }
        return;
    }

    float* sx = (float*)smem;                          // 384 f
    float* sy = sx + 384;
    float* sz = sy + 384;
    float* sq = sz + 384;
    unsigned char* sf = (unsigned char*)(sq + 384);    // 384 B
    float* red = (float*)(smem + 6528);                // 4 f

    const float* qc = ws + WS_QC;
    const int* flags = (const int*)(ws + WS_FLAG);
    const float* fiP = ws + WS_FIP;
    const float* fjP = ws + WS_FJP;

    const int pb = bi - 4;                 // 0..383
    const int b = pb / 96;                 // batch
    const int i0 = (pb % 96) * 4;          // first row in batch

    for (int j = t; j < LSEQ; j += 256) {
        int g = b * LSEQ + j;
        sx[j] = S[g * 3 + 0];
        sy[j] = S[g * 3 + 1];
        sz[j] = S[g * 3 + 2];
        sq[j] = qc[g];
        sf[j] = (unsigned char)flags[g];
    }
    __syncthreads();

    const int w = t >> 6, lane = t & 63;
    const int i = i0 + w;
    const int row = b * LSEQ + i;
    const float six = sx[i], siy = sy[i], siz = sz[i], qi = sq[i];
    const int fli = sf[i];
    const bool posi = (fli & 1) != 0, negi = (fli & 2) != 0;
    float* mrow = out + OUT_MASK + (long)row * LSEQ;

    const float* dvec = sW1 + 1280 * 128;
    const float dv0 = dvec[lane], dv1 = dvec[lane + 64];
    const float sb0 = sb1[lane], sb1v = sb1[lane + 64];
    const float w3l = sW3[lane];
    const float b2v = sb2[lane];
    const float b3v = sb3[0];

    float esum = 0.0f;
    for (int j0 = 0; j0 < LSEQ; j0 += 64) {
        const int j = j0 + lane;
        float dx = __fsub_rn(six, sx[j]);
        float dy = __fsub_rn(siy, sy[j]);
        float dz = __fsub_rn(siz, sz[j]);
        float d2 = __fadd_rn(__fadd_rn(__fmul_rn(dx, dx), __fmul_rn(dy, dy)), __fmul_rn(dz, dz));
        d2 = __fadd_rn(d2, 1e-12f);
        float D = __fsqrt_rn(d2);
        if (j > i && D < 15.0f && D > 0.0f) {
            float num = __fmul_rn(__fmul_rn(332.0f, qi), sq[j]);
            float den = __fmul_rn(__fmul_rn(20.0f, D), D);
            esum += __fdiv_rn(num, den);
        }
        int flj = sf[j];
        bool near = (D < 4.0f);
        bool need1 = near && posi && ((flj & 2) != 0);   // q[i][j]
        bool need2 = near && negi && ((flj & 1) != 0);   // q[j][i]
        int pk = (need1 ? 1 : 0) | (need2 ? 2 : 0);
        unsigned long long mb = __ballot(pk != 0);
        unsigned long long hitbits = 0ull;
        while (mb) {
            int jl = __ffsll((long long)mb) - 1;
            mb &= mb - 1ull;
            int pf = __shfl(pk, jl, 64);
            float Dj = __shfl(D, jl, 64);
            int gj = b * LSEQ + j0 + jl;
            bool hit = false;
            if (pf & 1) {
                float x = mlp_eval(fiP, fjP, row, gj, Dj, dv0, dv1, sb0, sb1v, b2v, w3l, sW2, lane);
                hit = (x + b3v) > 0.0f;
            }
            if (!hit && (pf & 2)) {
                float x = mlp_eval(fiP, fjP, gj, row, Dj, dv0, dv1, sb0, sb1v, b2v, w3l, sW2, lane);
                hit = (x + b3v) > 0.0f;
            }
            if (hit) hitbits |= (1ull << jl);
        }
        mrow[j] = ((hitbits >> lane) & 1ull) ? 1.0f : 0.0f;
    }
#pragma unroll
    for (int o = 32; o > 0; o >>= 1) esum += __shfl_xor(esum, o, 64);
    if (lane == 0) red[w] = esum;
    __syncthreads();
    if (t == 0) {
        float s = red[0] + red[1] + red[2] + red[3];
        atomicAdd(&out[OUT_EN + b], s);   // 96 blocks/address, 4 addresses
    }
}

extern "C" void kernel_launch(void* const* d_in, const int* in_sizes, int n_in,
                              void* d_out, int out_size, void* d_ws, size_t ws_size,
                              hipStream_t stream) {
    const float* X     = (const float*)d_in[0];
    const int*   seq   = (const int*)d_in[1];
    const float* S     = (const float*)d_in[2];
    const float* W1    = (const float*)d_in[3];
    const float* b1    = (const float*)d_in[4];
    const float* gam   = (const float*)d_in[5];
    const float* bet   = (const float*)d_in[6];
    const float* rmean = (const float*)d_in[7];
    const float* rvar  = (const float*)d_in[8];
    const float* W2    = (const float*)d_in[9];
    const float* b2    = (const float*)d_in[10];
    const float* W3    = (const float*)d_in[11];
    const float* b3    = (const float*)d_in[12];
    const float* sW1   = (const float*)d_in[13];
    const float* sb1   = (const float*)d_in[14];
    const float* sW2   = (const float*)d_in[15];
    const float* sb2   = (const float*)d_in[16];
    const float* sW3   = (const float*)d_in[17];
    const float* sb3   = (const float*)d_in[18];
    const float* c1w   = (const float*)d_in[19];
    const float* c1b   = (const float*)d_in[20];
    const float* c2w   = (const float*)d_in[21];
    const float* c2b   = (const float*)d_in[22];
    const float* c3w   = (const float*)d_in[23];
    const float* c3b   = (const float*)d_in[24];

    float* out = (float*)d_out;
    float* ws  = (float*)d_ws;

    hipLaunchKernelGGL(k1, dim3(864), dim3(256), 0, stream,
                       X, W1, sW1, b1, gam, bet, rmean, rvar, W2, b2, W3, b3,
                       seq, out, ws);
    hipLaunchKernelGGL(k2, dim3(388), dim3(256), 0, stream,
                       S, ws, sW1, sb1, sW2, sb2, sW3, sb3,
                       c1w, c1b, c2w, c2b, c3w, c3b, out);
}

// Round 9
// 158.306 us; speedup vs baseline: 1.0856x; 1.0856x over previous
//
#include <hip/hip_runtime.h>

#define LSEQ 384
#define NROWS 1536      // B*L
#define FDIM 640
#define HDIM 128
#define PART 196608     // 1536*128

// ws layout (float indices)
#define WS_H1P 0                 // 4 x PART (H1 split-K partials)
#define WS_FIP (4*PART)          // 4 x PART
#define WS_FJP (8*PART)          // 4 x PART
#define WS_FI  (12*PART)         // final fi
#define WS_FJ  (13*PART)         // final fj
#define WS_QC  (14*PART)
#define WS_FLAG (WS_QC + NROWS)   // int[1536]

// out layout (float indices)
#define OUT_PC    0
#define OUT_TC    4608
#define OUT_NET   9216
#define OUT_POT   10752
#define OUT_MASK  12288
#define OUT_EN    602112

// =========== Kernel 1: uniform split-K=4 GEMM, double-buffered ===========
// grid (48, 6, 4). BM=32, BN=64, BK=32, 256 threads, acc 2x4.
__global__ __launch_bounds__(256) void k_gemm(const float* __restrict__ X,
                                              const float* __restrict__ W1,
                                              const float* __restrict__ sW1,
                                              float* __restrict__ ws,
                                              float* __restrict__ out) {
    __shared__ float As[2 * 32 * 34];
    __shared__ float Bs[2 * 32 * 64];
    const int t = threadIdx.x;
    if (blockIdx.x == 0 && blockIdx.y == 0 && blockIdx.z == 0 && t < 4)
        out[OUT_EN + t] = 0.0f;        // energy zero (k2 atomicAdds later)

    const int m0 = blockIdx.x * 32;
    const int gy = blockIdx.y, kz = blockIdx.z;
    const int mat = gy >> 1, half = gy & 1, n0 = half * 64;
    const float* W = (mat == 0) ? W1 : (mat == 1 ? sW1 : sW1 + 640 * 128);
    float* O = ws + (mat == 0 ? WS_H1P : (mat == 1 ? WS_FIP : WS_FJP)) + kz * PART;

    const int a_r = t >> 3, a_c = (t & 7) * 4;
    const int b_r = t >> 4, b_c = (t & 15) * 4;
    const int tx = (t & 15) * 4, ty = (t >> 4) * 2;
    const int k0 = kz * 160;

    float acc[2][4] = {};

    float4 av  = *(const float4*)&X[(m0 + a_r) * FDIM + k0 + a_c];
    float4 bv0 = *(const float4*)&W[(k0 + b_r) * HDIM + n0 + b_c];
    float4 bv1 = *(const float4*)&W[(k0 + b_r + 16) * HDIM + n0 + b_c];
    As[(a_c + 0) * 34 + a_r] = av.x;
    As[(a_c + 1) * 34 + a_r] = av.y;
    As[(a_c + 2) * 34 + a_r] = av.z;
    As[(a_c + 3) * 34 + a_r] = av.w;
    *(float4*)&Bs[b_r * 64 + b_c]        = bv0;
    *(float4*)&Bs[(b_r + 16) * 64 + b_c] = bv1;
    __syncthreads();

    for (int it = 0; it < 5; it++) {
        const int buf = it & 1;
        if (it < 4) {
            const int kk = k0 + (it + 1) * 32;
            av  = *(const float4*)&X[(m0 + a_r) * FDIM + kk + a_c];
            bv0 = *(const float4*)&W[(kk + b_r) * HDIM + n0 + b_c];
            bv1 = *(const float4*)&W[(kk + b_r + 16) * HDIM + n0 + b_c];
        }
        const float* Ab = As + buf * 1088;
        const float* Bb = Bs + buf * 2048;
#pragma unroll
        for (int k = 0; k < 32; k++) {
            float2 a = *(const float2*)&Ab[k * 34 + ty];
            float4 b = *(const float4*)&Bb[k * 64 + tx];
            acc[0][0] = fmaf(a.x, b.x, acc[0][0]);
            acc[0][1] = fmaf(a.x, b.y, acc[0][1]);
            acc[0][2] = fmaf(a.x, b.z, acc[0][2]);
            acc[0][3] = fmaf(a.x, b.w, acc[0][3]);
            acc[1][0] = fmaf(a.y, b.x, acc[1][0]);
            acc[1][1] = fmaf(a.y, b.y, acc[1][1]);
            acc[1][2] = fmaf(a.y, b.z, acc[1][2]);
            acc[1][3] = fmaf(a.y, b.w, acc[1][3]);
        }
        if (it < 4) {
            float* Aw = As + (buf ^ 1) * 1088;
            float* Bw = Bs + (buf ^ 1) * 2048;
            Aw[(a_c + 0) * 34 + a_r] = av.x;
            Aw[(a_c + 1) * 34 + a_r] = av.y;
            Aw[(a_c + 2) * 34 + a_r] = av.z;
            Aw[(a_c + 3) * 34 + a_r] = av.w;
            *(float4*)&Bw[b_r * 64 + b_c]        = bv0;
            *(float4*)&Bw[(b_r + 16) * 64 + b_c] = bv1;
            __syncthreads();
        }
    }
#pragma unroll
    for (int r = 0; r < 2; r++) {
        float4 v = make_float4(acc[r][0], acc[r][1], acc[r][2], acc[r][3]);
        *(float4*)&O[(m0 + ty + r) * HDIM + n0 + tx] = v;
    }
}

// =========== Kernel 2: partial reduce + row epilogue ===========
__global__ __launch_bounds__(256) void k_row(float* __restrict__ ws,
                                             const float* __restrict__ b1,
                                             const float* __restrict__ gam,
                                             const float* __restrict__ bet,
                                             const float* __restrict__ rmean,
                                             const float* __restrict__ rvar,
                                             const float* __restrict__ W2,
                                             const float* __restrict__ b2,
                                             const float* __restrict__ W3,
                                             const float* __restrict__ b3,
                                             const int* __restrict__ seq,
                                             float* __restrict__ out) {
    const int t = threadIdx.x, w = t >> 6, lane = t & 63;
    const int row = blockIdx.x * 4 + w;
    const long base = (long)row * 128;
    const float* h1p = ws + WS_H1P;
    const float* fip = ws + WS_FIP;
    const float* fjp = ws + WS_FJP;

    {
        float fi0 = fip[base + lane] + fip[PART + base + lane]
                  + fip[2 * PART + base + lane] + fip[3 * PART + base + lane];
        float fi1 = fip[base + 64 + lane] + fip[PART + base + 64 + lane]
                  + fip[2 * PART + base + 64 + lane] + fip[3 * PART + base + 64 + lane];
        float fj0 = fjp[base + lane] + fjp[PART + base + lane]
                  + fjp[2 * PART + base + lane] + fjp[3 * PART + base + lane];
        float fj1 = fjp[base + 64 + lane] + fjp[PART + base + 64 + lane]
                  + fjp[2 * PART + base + 64 + lane] + fjp[3 * PART + base + 64 + lane];
        ws[WS_FI + base + lane]      = fi0;
        ws[WS_FI + base + 64 + lane] = fi1;
        ws[WS_FJ + base + lane]      = fj0;
        ws[WS_FJ + base + 64 + lane] = fj1;
    }

    float h0 = h1p[base + lane] + h1p[PART + base + lane]
             + h1p[2 * PART + base + lane] + h1p[3 * PART + base + lane];
    float h1 = h1p[base + 64 + lane] + h1p[PART + base + 64 + lane]
             + h1p[2 * PART + base + 64 + lane] + h1p[3 * PART + base + 64 + lane];
    h0 = fmaxf(h0 + b1[lane], 0.0f);
    h1 = fmaxf(h1 + b1[64 + lane], 0.0f);
    h0 = gam[lane]      * (h0 - rmean[lane])      / sqrtf(rvar[lane] + 1e-5f)      + bet[lane];
    h1 = gam[64 + lane] * (h1 - rmean[64 + lane]) / sqrtf(rvar[64 + lane] + 1e-5f) + bet[64 + lane];

    float acc = b2[lane];
#pragma unroll
    for (int cc = 0; cc < 64; cc++) {
        float wv0 = W2[cc * 64 + lane];
        float wv1 = W2[(cc + 64) * 64 + lane];
        float hv0 = __uint_as_float(__builtin_amdgcn_readlane(__float_as_uint(h0), cc));
        float hv1 = __uint_as_float(__builtin_amdgcn_readlane(__float_as_uint(h1), cc));
        acc = fmaf(hv0, wv0, acc);
        acc = fmaf(hv1, wv1, acc);
    }
    float h2 = fmaxf(acc, 0.0f);
    float x0 = h2 * W3[lane * 3 + 0];
    float x1 = h2 * W3[lane * 3 + 1];
    float x2 = h2 * W3[lane * 3 + 2];
#pragma unroll
    for (int o = 32; o > 0; o >>= 1) {
        x0 += __shfl_xor(x0, o, 64);
        x1 += __shfl_xor(x1, o, 64);
        x2 += __shfl_xor(x2, o, 64);
    }
    if (lane == 0) {
        float l0 = x0 + b3[0], l1 = x1 + b3[1], l2 = x2 + b3[2];
        float m = fmaxf(l0, fmaxf(l1, l2));
        float e0 = expf(l0 - m), e1 = expf(l1 - m), e2 = expf(l2 - m);
        float s = e0 + e1 + e2;
        float pc0 = e0 / s, pc1 = e1 / s, pc2 = e2 / s;
        out[OUT_PC + row * 3 + 0] = pc0;
        out[OUT_PC + row * 3 + 1] = pc1;
        out[OUT_PC + row * 3 + 2] = pc2;
        float net = pc0 - pc1;
        out[OUT_NET + row] = net;
        ws[WS_QC + row] = net;
        ((int*)(ws + WS_FLAG))[row] = (pc0 > pc2 ? 1 : 0) | (pc1 > pc2 ? 2 : 0);
        int sid = seq[row];
        float c0 = (sid == 6 || sid == 8 || sid == 14) ? 1.0f : 0.0f;
        float c1 = (sid == 2 || sid == 3) ? 1.0f : 0.0f;
        out[OUT_TC + row * 3 + 0] = c0;
        out[OUT_TC + row * 3 + 1] = c1;
        out[OUT_TC + row * 3 + 2] = (c0 == 0.0f && c1 == 0.0f) ? 1.0f : 0.0f;
    }
}

// =========== Kernel 3: conv + pair sweep + inline candidate MLP ===========
__device__ __forceinline__ float mlp_eval(const float* __restrict__ fi, const float* __restrict__ fj,
                                          int gi, int gj, float D,
                                          float dv0, float dv1, float sb0, float sb1v,
                                          float b2v, float w3l, const float* w2s, int lane) {
    float fi0 = fi[(long)gi * 128 + lane];
    float fi1 = fi[(long)gi * 128 + 64 + lane];
    float fj0 = fj[(long)gj * 128 + lane];
    float fj1 = fj[(long)gj * 128 + 64 + lane];
    float h0 = fmaxf(fi0 + fj0 + D * dv0 + sb0, 0.0f);
    float h1 = fmaxf(fi1 + fj1 + D * dv1 + sb1v, 0.0f);
    float a0 = 0.0f, a1 = 0.0f;
#pragma unroll
    for (int cc = 0; cc < 64; cc++) {
        float hv0 = __uint_as_float(__builtin_amdgcn_readlane(__float_as_uint(h0), cc));
        float hv1 = __uint_as_float(__builtin_amdgcn_readlane(__float_as_uint(h1), cc));
        a0 = fmaf(hv0, w2s[cc * 64 + lane], a0);
        a1 = fmaf(hv1, w2s[(cc + 64) * 64 + lane], a1);
    }
    float x = fmaxf(a0 + a1 + b2v, 0.0f) * w3l;
#pragma unroll
    for (int o = 32; o > 0; o >>= 1) x += __shfl_xor(x, o, 64);
    return x;
}

__global__ __launch_bounds__(256) void k2(const float* __restrict__ S,
                                          const float* __restrict__ ws,
                                          const float* __restrict__ sW1,
                                          const float* __restrict__ sb1,
                                          const float* __restrict__ sW2,
                                          const float* __restrict__ sb2,
                                          const float* __restrict__ sW3,
                                          const float* __restrict__ sb3,
                                          const float* __restrict__ c1w, const float* __restrict__ c1b,
                                          const float* __restrict__ c2w, const float* __restrict__ c2b,
                                          const float* __restrict__ c3w, const float* __restrict__ c3b,
                                          float* __restrict__ out) {
    __shared__ char smem[40960];
    const int t = threadIdx.x;
    const int bi = blockIdx.x;

    if (bi < 4) {
        float* p0 = (float*)smem;
        float* p1 = p0 + 388;
        float* p2 = p1 + 16 * 386;
        const int b = bi;
        for (int j = t; j < LSEQ; j += 256) p0[j + 2] = out[OUT_NET + b * LSEQ + j];
        if (t < 2) { p0[t] = 0.0f; p0[LSEQ + 2 + t] = 0.0f; }
        if (t < 16) { p1[t * 386] = 0.0f; p1[t * 386 + 385] = 0.0f; }
        if (t < 8)  { p2[t * 386] = 0.0f; p2[t * 386 + 385] = 0.0f; }
        __syncthreads();
        for (int pos = t; pos < LSEQ; pos += 256) {
#pragma unroll
            for (int o = 0; o < 16; o++) {
                float acc = c1b[o];
#pragma unroll
                for (int k = 0; k < 5; k++) acc = fmaf(p0[pos + k], c1w[o * 5 + k], acc);
                p1[o * 386 + pos + 1] = fmaxf(acc, 0.0f);
            }
        }
        __syncthreads();
        for (int pos = t; pos < LSEQ; pos += 256) {
#pragma unroll
            for (int o = 0; o < 8; o++) {
                float acc = c2b[o];
                for (int i = 0; i < 16; i++)
#pragma unroll
                    for (int k = 0; k < 3; k++)
                        acc = fmaf(p1[i * 386 + pos + k], c2w[(o * 16 + i) * 3 + k], acc);
                p2[o * 386 + pos + 1] = fmaxf(acc, 0.0f);
            }
        }
        __syncthreads();
        for (int pos = t; pos < LSEQ; pos += 256) {
            float acc = c3b[0];
            for (int i = 0; i < 8; i++)
#pragma unroll
                for (int k = 0; k < 3; k++)
                    acc = fmaf(p2[i * 386 + pos + k], c3w[i * 3 + k], acc);
            out[OUT_POT + b * LSEQ + pos] = acc;
        }
        return;
    }

    float* sx = (float*)smem;
    float* sy = sx + 384;
    float* sz = sy + 384;
    float* sq = sz + 384;
    unsigned int* clist = (unsigned int*)(sq + 384);
    unsigned char* sf = (unsigned char*)(smem + 7680);
    float* red = (float*)(smem + 8064);
    int* cntL = (int*)(smem + 8080);
    float* w2s = (float*)(smem + 8192);

    const float* qc = ws + WS_QC;
    const int* flags = (const int*)(ws + WS_FLAG);
    const float* fi = ws + WS_FI;
    const float* fj = ws + WS_FJ;

    const int row = bi - 4;
    const int b = row / LSEQ;
    const int i = row - b * LSEQ;

    for (int j = t; j < LSEQ; j += 256) {
        int g = b * LSEQ + j;
        sx[j] = S[g * 3 + 0];
        sy[j] = S[g * 3 + 1];
        sz[j] = S[g * 3 + 2];
        sq[j] = qc[g];
        sf[j] = (unsigned char)flags[g];
    }
    if (t == 0) *cntL = 0;
    __syncthreads();

    const float six = sx[i], siy = sy[i], siz = sz[i], qi = sq[i];
    const int fli = sf[i];
    const bool posi = (fli & 1) != 0, negi = (fli & 2) != 0;
    const int lane = t & 63, w = t >> 6;
    float esum = 0.0f;
    float* mrow = out + OUT_MASK + (long)row * LSEQ;

    for (int j = t; j < LSEQ; j += 256) {
        float dx = __fsub_rn(six, sx[j]);
        float dy = __fsub_rn(siy, sy[j]);
        float dz = __fsub_rn(siz, sz[j]);
        float d2 = __fadd_rn(__fadd_rn(__fmul_rn(dx, dx), __fmul_rn(dy, dy)), __fmul_rn(dz, dz));
        d2 = __fadd_rn(d2, 1e-12f);
        float D = __fsqrt_rn(d2);
        mrow[j] = 0.0f;
        if (j > i && D < 15.0f && D > 0.0f) {
            float num = __fmul_rn(__fmul_rn(332.0f, qi), sq[j]);
            float den = __fmul_rn(__fmul_rn(20.0f, D), D);
            esum += __fdiv_rn(num, den);
        }
        int flj = sf[j];
        bool near = (D < 4.0f);
        bool need1 = near && posi && ((flj & 2) != 0);
        bool need2 = near && negi && ((flj & 1) != 0);
        if (need1 || need2) {
            int p = atomicAdd(cntL, 1);
            clist[p] = (unsigned int)j | (need1 ? 512u : 0u) | (need2 ? 1024u : 0u);
        }
    }
#pragma unroll
    for (int o = 32; o > 0; o >>= 1) esum += __shfl_xor(esum, o, 64);
    if (lane == 0) red[w] = esum;
    __syncthreads();
    if (t == 0) {
        float s = red[0] + red[1] + red[2] + red[3];
        atomicAdd(&out[OUT_EN + b], s);
    }

    int nc = *cntL;   // valid: barrier above
    if (nc == 0) return;

    for (int idx = t; idx < 2048; idx += 256)
        ((float4*)w2s)[idx] = ((const float4*)sW2)[idx];
    const float* dvec = sW1 + 1280 * 128;
    const float dv0 = dvec[lane], dv1 = dvec[lane + 64];
    const float sb0 = sb1[lane], sb1v = sb1[lane + 64];
    const float w3l = sW3[lane];
    const float b2v = sb2[lane];
    const float b3v = sb3[0];
    __syncthreads();

    for (int c = w; c < nc; c += 4) {
        unsigned int e = clist[c];
        int j = (int)(e & 511u);
        bool need1 = (e & 512u) != 0, need2 = (e & 1024u) != 0;
        float dx = __fsub_rn(six, sx[j]);
        float dy = __fsub_rn(siy, sy[j]);
        float dz = __fsub_rn(siz, sz[j]);
        float d2 = __fadd_rn(__fadd_rn(__fmul_rn(dx, dx), __fmul_rn(dy, dy)), __fmul_rn(dz, dz));
        d2 = __fadd_rn(d2, 1e-12f);
        float D = __fsqrt_rn(d2);
        int gi = row, gj = b * LSEQ + j;
        bool hit = false;
        if (need1) {
            float x = mlp_eval(fi, fj, gi, gj, D, dv0, dv1, sb0, sb1v, b2v, w3l, w2s, lane);
            hit = (x + b3v) > 0.0f;
        }
        if (!hit && need2) {
            float x = mlp_eval(fi, fj, gj, gi, D, dv0, dv1, sb0, sb1v, b2v, w3l, w2s, lane);
            hit = (x + b3v) > 0.0f;
        }
        if (hit && lane == 0) mrow[j] = 1.0f;
    }
}

extern "C" void kernel_launch(void* const* d_in, const int* in_sizes, int n_in,
                              void* d_out, int out_size, void* d_ws, size_t ws_size,
                              hipStream_t stream) {
    const float* X     = (const float*)d_in[0];
    const int*   seq   = (const int*)d_in[1];
    const float* S     = (const float*)d_in[2];
    const float* W1    = (const float*)d_in[3];
    const float* b1    = (const float*)d_in[4];
    const float* gam   = (const float*)d_in[5];
    const float* bet   = (const float*)d_in[6];
    const float* rmean = (const float*)d_in[7];
    const float* rvar  = (const float*)d_in[8];
    const float* W2    = (const float*)d_in[9];
    const float* b2    = (const float*)d_in[10];
    const float* W3    = (const float*)d_in[11];
    const float* b3    = (const float*)d_in[12];
    const float* sW1   = (const float*)d_in[13];
    const float* sb1   = (const float*)d_in[14];
    const float* sW2   = (const float*)d_in[15];
    const float* sb2   = (const float*)d_in[16];
    const float* sW3   = (const float*)d_in[17];
    const float* sb3   = (const float*)d_in[18];
    const float* c1w   = (const float*)d_in[19];
    const float* c1b   = (const float*)d_in[20];
    const float* c2w   = (const float*)d_in[21];
    const float* c2b   = (const float*)d_in[22];
    const float* c3w   = (const float*)d_in[23];
    const float* c3b   = (const float*)d_in[24];

    float* out = (float*)d_out;
    float* ws  = (float*)d_ws;

    hipLaunchKernelGGL(k_gemm, dim3(48, 6, 4), dim3(256), 0, stream, X, W1, sW1, ws, out);
    hipLaunchKernelGGL(k_row, dim3(384), dim3(256), 0, stream,
                       ws, b1, gam, bet, rmean, rvar, W2, b2, W3, b3, seq, out);
    hipLaunchKernelGGL(k2, dim3(1540), dim3(256), 0, stream,
                       S, ws, sW1, sb1, sW2, sb2, sW3, sb3,
                       c1w, c1b, c2w, c2b, c3w, c3b, out);
}